// Round 2
// baseline (5665.485 us; speedup 1.0000x reference)
//
#include <hip/hip_runtime.h>

#define N_IN    262144
#define N_OUT   393216
#define M_PAIRS 262144
#define KK      27
#define CIN     32
#define COUT    64
#define BN_EPS  1e-5f

#define TOTAL_E      (KK * M_PAIRS)      // 7,077,888
#define ROWS_PER_BIN 128
#define NR           (N_OUT / ROWS_PER_BIN)  // 3072
#define NBINS        (NR * KK)               // 82944

typedef unsigned int u32;

// ---------------- Phase A1: histogram over (range, k) bins ----------------
__global__ __launch_bounds__(256) void bin_count(
    const int* __restrict__ out_idx, u32* __restrict__ cnt)
{
    const int stride = gridDim.x * 256;
    for (int e = blockIdx.x * 256 + threadIdx.x; e < TOTAL_E; e += stride) {
        const int k = e >> 18;                 // M_PAIRS = 2^18
        const int r = out_idx[e] >> 7;         // 128 rows per bin
        atomicAdd(&cnt[r * KK + k], 1u);
    }
}

// ---------------- Phase A2: exclusive scan of 82944 counts ----------------
// Single block, 1024 threads, 81 chunks. Writes offsets (off) and resets
// cnt to the exclusive prefix so it can serve as allocation cursors in A3.
__global__ __launch_bounds__(1024) void scan_bins(
    u32* __restrict__ cnt, u32* __restrict__ off)
{
    __shared__ u32 sh[1024];
    __shared__ u32 carry;
    const int t = threadIdx.x;
    if (t == 0) carry = 0;
    __syncthreads();
    for (int chunk = 0; chunk < NBINS / 1024; ++chunk) {
        const int i = chunk * 1024 + t;
        const u32 v = cnt[i];
        sh[t] = v;
        __syncthreads();
        #pragma unroll
        for (int d = 1; d < 1024; d <<= 1) {
            const u32 add = (t >= d) ? sh[t - d] : 0u;
            __syncthreads();
            sh[t] += add;
            __syncthreads();
        }
        const u32 excl = sh[t] - v + carry;
        off[i] = excl;
        cnt[i] = excl;          // cursor for A3
        __syncthreads();
        if (t == 1023) carry += sh[1023];
        __syncthreads();
    }
    if (t == 0) off[NBINS] = carry;  // sentinel == TOTAL_E
}

// ---------------- Phase A3: scatter packed records into segments ----------
// record = in_i (18b) | local_out (7b) << 18
__global__ __launch_bounds__(256) void bin_scatter(
    const int* __restrict__ in_idx, const int* __restrict__ out_idx,
    u32* __restrict__ cursor, u32* __restrict__ rec)
{
    const int stride = gridDim.x * 256;
    for (int e = blockIdx.x * 256 + threadIdx.x; e < TOTAL_E; e += stride) {
        const int k    = e >> 18;
        const int oi   = out_idx[e];
        const int ii   = in_idx[e];
        const int bin  = (oi >> 7) * KK + k;
        const u32 pos  = atomicAdd(&cursor[bin], 1u);
        rec[pos] = (u32)ii | ((u32)(oi & 127) << 18);
    }
}

// ---------------- Phase B: per-range accumulate + fused BN stats ----------
__global__ __launch_bounds__(256) void range_accum(
    const float* __restrict__ data,   // [N_IN, CIN]
    const float* __restrict__ W,      // [K, CIN, COUT]
    const u32*  __restrict__ off,     // [NBINS+1]
    const u32*  __restrict__ rec,     // [TOTAL_E]
    float*      __restrict__ out,     // [N_OUT, COUT]
    float*      __restrict__ stats)   // [128]
{
    __shared__ float acc[ROWS_PER_BIN * COUT];  // 32 KB
    __shared__ float Wl[CIN * COUT];            // 8 KB
    const int r    = blockIdx.x;
    const int tid  = threadIdx.x;
    const int wave = tid >> 6;
    const int lane = tid & 63;

    for (int i = tid; i < ROWS_PER_BIN * COUT; i += 256) acc[i] = 0.0f;

    for (int k = 0; k < KK; ++k) {
        __syncthreads();
        for (int i = tid; i < CIN * COUT; i += 256)
            Wl[i] = W[k * CIN * COUT + i];
        __syncthreads();

        const u32 begin = off[r * KK + k];
        const u32 end   = off[r * KK + k + 1];
        for (u32 idx = begin + wave; idx < end; idx += 4) {
            const u32 rc   = rec[idx];
            const int in_i = (int)(rc & 0x3FFFFu);
            const int lo   = (int)(rc >> 18);
            const float val = data[in_i * CIN + (lane & 31)];
            float a = 0.0f;
            #pragma unroll
            for (int c = 0; c < CIN; ++c) {
                const float rv = __shfl(val, c, 64);
                a = fmaf(rv, Wl[c * COUT + lane], a);
            }
            atomicAdd(&acc[lo * COUT + lane], a);
        }
    }
    __syncthreads();

    // fused BN partial stats: thread t covers channel (t&63), rows t>>6 :: 4
    {
        const int c = tid & 63;
        float s = 0.0f, sq = 0.0f;
        for (int row = tid >> 6; row < ROWS_PER_BIN; row += 4) {
            const float x = acc[row * COUT + c];
            s += x; sq += x * x;
        }
        Wl[tid]       = s;
        Wl[256 + tid] = sq;
        __syncthreads();
        if (tid < 64) {
            const float ts = Wl[tid] + Wl[tid + 64] + Wl[tid + 128] + Wl[tid + 192];
            const float tq = Wl[256 + tid] + Wl[320 + tid] + Wl[384 + tid] + Wl[448 + tid];
            atomicAdd(&stats[tid], ts);
            atomicAdd(&stats[64 + tid], tq);
        }
    }

    // coalesced float4 store of the 128x64 block
    const float4* a4 = (const float4*)acc;
    float4* o4 = (float4*)out;
    for (int i = tid; i < ROWS_PER_BIN * COUT / 4; i += 256)
        o4[r * (ROWS_PER_BIN * COUT / 4) + i] = a4[i];
}

// ---------------- BN normalize (in place) ----------------
__global__ __launch_bounds__(256) void bn_norm(
    float* __restrict__ out, const float* __restrict__ stats,
    const float* __restrict__ gamma, const float* __restrict__ beta)
{
    __shared__ float scale[COUT], bias[COUT];
    if (threadIdx.x < COUT) {
        const int c = threadIdx.x;
        const float invN = 1.0f / (float)N_OUT;
        const float mean = stats[c] * invN;
        const float var  = stats[64 + c] * invN - mean * mean;
        const float inv  = rsqrtf(var + BN_EPS);
        const float g    = gamma[c];
        scale[c] = inv * g;
        bias[c]  = beta[c] - mean * inv * g;
    }
    __syncthreads();

    const int tid    = blockIdx.x * blockDim.x + threadIdx.x;
    const int stride = gridDim.x * blockDim.x;
    const int total4 = N_OUT * COUT / 4;
    float4* o4 = (float4*)out;
    for (int i = tid; i < total4; i += stride) {
        float4 v = o4[i];
        const int c0 = (i * 4) & 63;
        v.x = v.x * scale[c0 + 0] + bias[c0 + 0];
        v.y = v.y * scale[c0 + 1] + bias[c0 + 1];
        v.z = v.z * scale[c0 + 2] + bias[c0 + 2];
        v.w = v.w * scale[c0 + 3] + bias[c0 + 3];
        o4[i] = v;
    }
}

// ---------------- Fallback (round-1 path) if workspace too small ----------
__global__ __launch_bounds__(256) void conv_scatter_fb(
    const float* __restrict__ data, const float* __restrict__ W,
    const int* __restrict__ in_idx, const int* __restrict__ out_idx,
    float* __restrict__ out)
{
    __shared__ float Wlds[CIN * COUT];
    const int k   = blockIdx.x / 256;
    const int blk = blockIdx.x % 256;
    for (int i = threadIdx.x; i < CIN * COUT; i += 256)
        Wlds[i] = W[k * CIN * COUT + i];
    __syncthreads();
    const int wave = threadIdx.x >> 6;
    const int lane = threadIdx.x & 63;
    const int base = k * M_PAIRS + blk * 1024 + wave * 256;
    for (int p = 0; p < 256; ++p) {
        const int in_i  = in_idx[base + p];
        const int out_i = out_idx[base + p];
        const float val = data[in_i * CIN + (lane & 31)];
        float a = 0.0f;
        #pragma unroll
        for (int c = 0; c < CIN; ++c)
            a = fmaf(__shfl(val, c, 64), Wlds[c * COUT + lane], a);
        atomicAdd(&out[out_i * COUT + lane], a);
    }
}

__global__ __launch_bounds__(256) void bn_stats_fb(
    const float* __restrict__ out, float* __restrict__ stats)
{
    const int tid    = blockIdx.x * 256 + threadIdx.x;
    const int stride = gridDim.x * 256;
    float s = 0.0f, sq = 0.0f;
    for (int i = tid; i < N_OUT * COUT; i += stride) {
        const float x = out[i]; s += x; sq += x * x;
    }
    __shared__ float ls[256], lsq[256];
    ls[threadIdx.x] = s; lsq[threadIdx.x] = sq;
    __syncthreads();
    if (threadIdx.x < 64) {
        const int c = threadIdx.x;
        atomicAdd(&stats[c],      ls[c] + ls[c+64] + ls[c+128] + ls[c+192]);
        atomicAdd(&stats[64 + c], lsq[c] + lsq[c+64] + lsq[c+128] + lsq[c+192]);
    }
}

extern "C" void kernel_launch(void* const* d_in, const int* in_sizes, int n_in,
                              void* d_out, int out_size, void* d_ws, size_t ws_size,
                              hipStream_t stream) {
    const float* data    = (const float*)d_in[0];
    const float* W       = (const float*)d_in[1];
    const float* gamma   = (const float*)d_in[2];
    const float* beta    = (const float*)d_in[3];
    const int*   in_idx  = (const int*)d_in[4];
    const int*   out_idx = (const int*)d_in[5];
    float* out = (float*)d_out;

    // workspace layout
    u32* cnt = (u32*)d_ws;                        // NBINS   (counts -> cursors)
    u32* off = cnt + NBINS;                       // NBINS+1 (offsets + sentinel)
    u32* rec = off + NBINS + 1;                   // TOTAL_E packed records
    float* stats = (float*)(rec + TOTAL_E);       // 128
    const size_t ws_needed = (size_t)(NBINS + NBINS + 1 + TOTAL_E + 128) * 4;

    if (ws_size >= ws_needed) {
        hipMemsetAsync(cnt, 0, (size_t)NBINS * sizeof(u32), stream);
        hipMemsetAsync(stats, 0, 128 * sizeof(float), stream);

        bin_count<<<4096, 256, 0, stream>>>(out_idx, cnt);
        scan_bins<<<1, 1024, 0, stream>>>(cnt, off);
        bin_scatter<<<4096, 256, 0, stream>>>(in_idx, out_idx, cnt, rec);
        range_accum<<<NR, 256, 0, stream>>>(data, W, off, rec, out, stats);
        bn_norm<<<2048, 256, 0, stream>>>(out, stats, gamma, beta);
    } else {
        float* stats_fb = (float*)d_ws;           // needs only 512 B
        hipMemsetAsync(d_out, 0, (size_t)N_OUT * COUT * sizeof(float), stream);
        hipMemsetAsync(stats_fb, 0, 128 * sizeof(float), stream);
        conv_scatter_fb<<<KK * 256, 256, 0, stream>>>(data, W, in_idx, out_idx, out);
        bn_stats_fb<<<1024, 256, 0, stream>>>(out, stats_fb);
        bn_norm<<<2048, 256, 0, stream>>>(out, stats_fb, gamma, beta);
    }
}

// Round 3
// 3199.327 us; speedup vs baseline: 1.7708x; 1.7708x over previous
//
#include <hip/hip_runtime.h>
#include <hip/hip_bf16.h>

#define N_IN    262144
#define N_OUT   393216
#define M_PAIRS 262144
#define KK      27
#define CIN     32
#define COUT    64
#define BN_EPS  1e-5f

#define TOTAL_E      (KK * M_PAIRS)          // 7,077,888
#define ROWS_PER_BIN 128
#define NR           (N_OUT / ROWS_PER_BIN)  // 3072
#define NBINS        (NR * KK)               // 82944 = 81 * 1024

typedef unsigned int u32;
typedef float f32x4 __attribute__((ext_vector_type(4)));
typedef short s16x8 __attribute__((ext_vector_type(8)));

static __device__ __forceinline__ short f2bf(float f) {
    __hip_bfloat16 h = __float2bfloat16(f);
    return *reinterpret_cast<short*>(&h);
}

// ---------------- W convert: f32 [K][CIN][COUT] -> bf16 [K][COUT][CIN] ------
__global__ __launch_bounds__(256) void w_convert(
    const float* __restrict__ W, short* __restrict__ Wt)
{
    const int t = blockIdx.x * 256 + threadIdx.x;
    if (t >= KK * COUT * CIN) return;
    const int k    = t / (COUT * CIN);
    const int rem  = t % (COUT * CIN);
    const int co   = rem / CIN;
    const int ci   = rem % CIN;
    Wt[t] = f2bf(W[k * CIN * COUT + ci * COUT + co]);
}

// ---------------- Phase A1: histogram over (range, k) bins ----------------
__global__ __launch_bounds__(256) void bin_count(
    const int4* __restrict__ out_idx4, u32* __restrict__ cnt)
{
    const int stride = gridDim.x * 256;
    for (int e4 = blockIdx.x * 256 + threadIdx.x; e4 < TOTAL_E / 4; e4 += stride) {
        const int k = e4 >> 16;              // e = 4*e4 ; k = e >> 18
        const int4 v = out_idx4[e4];
        atomicAdd(&cnt[(v.x >> 7) * KK + k], 1u);
        atomicAdd(&cnt[(v.y >> 7) * KK + k], 1u);
        atomicAdd(&cnt[(v.z >> 7) * KK + k], 1u);
        atomicAdd(&cnt[(v.w >> 7) * KK + k], 1u);
    }
}

// ---------------- Phase A2: hierarchical exclusive scan (82944 = 81*1024) --
__global__ __launch_bounds__(1024) void scan_part(
    const u32* __restrict__ cnt, u32* __restrict__ partial)
{
    __shared__ u32 sh[1024];
    sh[threadIdx.x] = cnt[blockIdx.x * 1024 + threadIdx.x];
    __syncthreads();
    for (int d = 512; d > 0; d >>= 1) {
        if (threadIdx.x < d) sh[threadIdx.x] += sh[threadIdx.x + d];
        __syncthreads();
    }
    if (threadIdx.x == 0) partial[blockIdx.x] = sh[0];
}

__global__ void scan_small(u32* __restrict__ partial)  // 1 thread: 81 entries
{
    u32 run = 0;
    for (int i = 0; i < NBINS / 1024; ++i) {
        const u32 v = partial[i];
        partial[i] = run;
        run += v;
    }
}

__global__ __launch_bounds__(1024) void scan_final(
    u32* __restrict__ cnt, u32* __restrict__ off, const u32* __restrict__ partial)
{
    __shared__ u32 sh[1024];
    const int t = threadIdx.x;
    const int i = blockIdx.x * 1024 + t;
    const u32 v = cnt[i];
    sh[t] = v;
    __syncthreads();
    for (int d = 1; d < 1024; d <<= 1) {
        const u32 add = (t >= d) ? sh[t - d] : 0u;
        __syncthreads();
        sh[t] += add;
        __syncthreads();
    }
    const u32 excl = sh[t] - v + partial[blockIdx.x];
    off[i] = excl;
    cnt[i] = excl;                 // cursor for A3
    if (blockIdx.x == 0 && t == 0) off[NBINS] = TOTAL_E;
}

// ---------------- Phase A3: scatter packed records into segments ----------
// record = in_i (18b) | local_out (7b) << 18
__global__ __launch_bounds__(256) void bin_scatter(
    const int4* __restrict__ in_idx4, const int4* __restrict__ out_idx4,
    u32* __restrict__ cursor, u32* __restrict__ rec)
{
    const int stride = gridDim.x * 256;
    for (int e4 = blockIdx.x * 256 + threadIdx.x; e4 < TOTAL_E / 4; e4 += stride) {
        const int k  = e4 >> 16;
        const int4 oi = out_idx4[e4];
        const int4 ii = in_idx4[e4];
        {
            const u32 pos = atomicAdd(&cursor[(oi.x >> 7) * KK + k], 1u);
            rec[pos] = (u32)ii.x | ((u32)(oi.x & 127) << 18);
        }
        {
            const u32 pos = atomicAdd(&cursor[(oi.y >> 7) * KK + k], 1u);
            rec[pos] = (u32)ii.y | ((u32)(oi.y & 127) << 18);
        }
        {
            const u32 pos = atomicAdd(&cursor[(oi.z >> 7) * KK + k], 1u);
            rec[pos] = (u32)ii.z | ((u32)(oi.z & 127) << 18);
        }
        {
            const u32 pos = atomicAdd(&cursor[(oi.w >> 7) * KK + k], 1u);
            rec[pos] = (u32)ii.w | ((u32)(oi.w & 127) << 18);
        }
    }
}

// ---------------- Phase B: MFMA per-range accumulate + fused BN stats ------
// Per wave: 16 records -> A frag (16x32 bf16), 4 B frags (32x16) held in regs
// per k, 4x mfma_f32_16x16x32_bf16 -> D (16 recs x 64 couts) -> LDS scatter.
__global__ __launch_bounds__(256) void range_accum(
    const float* __restrict__ data,   // [N_IN, CIN] f32
    const short* __restrict__ Wt,     // [K, COUT, CIN] bf16 bits
    const u32*  __restrict__ off,     // [NBINS+1]
    const u32*  __restrict__ rec,     // [TOTAL_E + pad]
    float*      __restrict__ out,     // [N_OUT, COUT]
    float*      __restrict__ stats)   // [128]
{
    __shared__ float acc[ROWS_PER_BIN * COUT];  // 32 KB
    __shared__ float sred[512];

    const int r    = blockIdx.x;
    const int tid  = threadIdx.x;
    const int wave = tid >> 6;
    const int lane = tid & 63;
    const int jrow = lane & 15;      // A row / D col index
    const int kq   = lane >> 4;      // 0..3 : k-chunk / D row group

    for (int i = tid; i < ROWS_PER_BIN * COUT; i += 256) acc[i] = 0.0f;
    __syncthreads();

    for (int k = wave; k < KK; k += 4) {
        // B fragments: B[kk][n] with n = jrow, kk = kq*8 + j  -> Wt[k][t*16+jrow][kq*8 + j]
        const short* wb = Wt + (k * COUT + jrow) * CIN + kq * 8;
        const s16x8 b0 = *(const s16x8*)(wb + 0 * 16 * CIN);
        const s16x8 b1 = *(const s16x8*)(wb + 1 * 16 * CIN);
        const s16x8 b2 = *(const s16x8*)(wb + 2 * 16 * CIN);
        const s16x8 b3 = *(const s16x8*)(wb + 3 * 16 * CIN);

        const u32 begin = off[r * KK + k];
        const u32 end   = off[r * KK + k + 1];
        for (u32 base = begin; base < end; base += 16) {
            const u32 slot   = base + (u32)jrow;
            const bool valid = slot < end;
            const u32 rc     = rec[slot];            // may over-read into pad
            const int in_i   = (int)(rc & 0x3FFFFu); // masked -> always in bounds
            const float* dp  = data + in_i * CIN + kq * 8;
            f32x4 x0 = *(const f32x4*)dp;
            f32x4 x1 = *(const f32x4*)(dp + 4);
            if (!valid) {
                x0 = (f32x4){0.f, 0.f, 0.f, 0.f};
                x1 = (f32x4){0.f, 0.f, 0.f, 0.f};
            }
            s16x8 a;
            a[0] = f2bf(x0[0]); a[1] = f2bf(x0[1]); a[2] = f2bf(x0[2]); a[3] = f2bf(x0[3]);
            a[4] = f2bf(x1[0]); a[5] = f2bf(x1[1]); a[6] = f2bf(x1[2]); a[7] = f2bf(x1[3]);

            const f32x4 z = {0.f, 0.f, 0.f, 0.f};
            const f32x4 d0 = __builtin_amdgcn_mfma_f32_16x16x32_bf16(a, b0, z, 0, 0, 0);
            const f32x4 d1 = __builtin_amdgcn_mfma_f32_16x16x32_bf16(a, b1, z, 0, 0, 0);
            const f32x4 d2 = __builtin_amdgcn_mfma_f32_16x16x32_bf16(a, b2, z, 0, 0, 0);
            const f32x4 d3 = __builtin_amdgcn_mfma_f32_16x16x32_bf16(a, b3, z, 0, 0, 0);

            // D row = kq*4 + g (record), D col = jrow (cout within tile)
            #pragma unroll
            for (int g = 0; g < 4; ++g) {
                const u32 rr = rec[base + (u32)(kq * 4 + g)];
                const int lo = (int)((rr >> 18) & 127u);
                float* ap = acc + lo * COUT + jrow;
                atomicAdd(ap + 0,  d0[g]);
                atomicAdd(ap + 16, d1[g]);
                atomicAdd(ap + 32, d2[g]);
                atomicAdd(ap + 48, d3[g]);
            }
        }
    }
    __syncthreads();

    // fused BN partial stats: thread t covers channel (t&63), rows (t>>6)::4
    {
        const int c = tid & 63;
        float s = 0.0f, sq = 0.0f;
        for (int row = tid >> 6; row < ROWS_PER_BIN; row += 4) {
            const float x = acc[row * COUT + c];
            s += x; sq += x * x;
        }
        sred[tid]       = s;
        sred[256 + tid] = sq;
        __syncthreads();
        if (tid < 64) {
            atomicAdd(&stats[tid],      sred[tid] + sred[tid + 64] + sred[tid + 128] + sred[tid + 192]);
            atomicAdd(&stats[64 + tid], sred[256 + tid] + sred[320 + tid] + sred[384 + tid] + sred[448 + tid]);
        }
    }

    // coalesced float4 store of the 128x64 block
    const float4* a4 = (const float4*)acc;
    float4* o4 = (float4*)out;
    for (int i = tid; i < ROWS_PER_BIN * COUT / 4; i += 256)
        o4[r * (ROWS_PER_BIN * COUT / 4) + i] = a4[i];
}

// ---------------- BN normalize (in place) ----------------
__global__ __launch_bounds__(256) void bn_norm(
    float* __restrict__ out, const float* __restrict__ stats,
    const float* __restrict__ gamma, const float* __restrict__ beta)
{
    __shared__ float scale[COUT], bias[COUT];
    if (threadIdx.x < COUT) {
        const int c = threadIdx.x;
        const float invN = 1.0f / (float)N_OUT;
        const float mean = stats[c] * invN;
        const float var  = stats[64 + c] * invN - mean * mean;
        const float inv  = rsqrtf(var + BN_EPS);
        const float g    = gamma[c];
        scale[c] = inv * g;
        bias[c]  = beta[c] - mean * inv * g;
    }
    __syncthreads();

    const int tid    = blockIdx.x * blockDim.x + threadIdx.x;
    const int stride = gridDim.x * blockDim.x;
    const int total4 = N_OUT * COUT / 4;
    float4* o4 = (float4*)out;
    for (int i = tid; i < total4; i += stride) {
        float4 v = o4[i];
        const int c0 = (i * 4) & 63;
        v.x = v.x * scale[c0 + 0] + bias[c0 + 0];
        v.y = v.y * scale[c0 + 1] + bias[c0 + 1];
        v.z = v.z * scale[c0 + 2] + bias[c0 + 2];
        v.w = v.w * scale[c0 + 3] + bias[c0 + 3];
        o4[i] = v;
    }
}

// ---------------- Fallback (round-1 path) if workspace too small ----------
__global__ __launch_bounds__(256) void conv_scatter_fb(
    const float* __restrict__ data, const float* __restrict__ W,
    const int* __restrict__ in_idx, const int* __restrict__ out_idx,
    float* __restrict__ out)
{
    __shared__ float Wlds[CIN * COUT];
    const int k   = blockIdx.x / 256;
    const int blk = blockIdx.x % 256;
    for (int i = threadIdx.x; i < CIN * COUT; i += 256)
        Wlds[i] = W[k * CIN * COUT + i];
    __syncthreads();
    const int wave = threadIdx.x >> 6;
    const int lane = threadIdx.x & 63;
    const int base = k * M_PAIRS + blk * 1024 + wave * 256;
    for (int p = 0; p < 256; ++p) {
        const int in_i  = in_idx[base + p];
        const int out_i = out_idx[base + p];
        const float val = data[in_i * CIN + (lane & 31)];
        float a = 0.0f;
        #pragma unroll
        for (int c = 0; c < CIN; ++c)
            a = fmaf(__shfl(val, c, 64), Wlds[c * COUT + lane], a);
        atomicAdd(&out[out_i * COUT + lane], a);
    }
}

__global__ __launch_bounds__(256) void bn_stats_fb(
    const float* __restrict__ out, float* __restrict__ stats)
{
    const int tid    = blockIdx.x * 256 + threadIdx.x;
    const int stride = gridDim.x * 256;
    float s = 0.0f, sq = 0.0f;
    for (int i = tid; i < N_OUT * COUT; i += stride) {
        const float x = out[i]; s += x; sq += x * x;
    }
    __shared__ float ls[256], lsq[256];
    ls[threadIdx.x] = s; lsq[threadIdx.x] = sq;
    __syncthreads();
    if (threadIdx.x < 64) {
        const int c = threadIdx.x;
        atomicAdd(&stats[c],      ls[c] + ls[c+64] + ls[c+128] + ls[c+192]);
        atomicAdd(&stats[64 + c], lsq[c] + lsq[c+64] + lsq[c+128] + lsq[c+192]);
    }
}

extern "C" void kernel_launch(void* const* d_in, const int* in_sizes, int n_in,
                              void* d_out, int out_size, void* d_ws, size_t ws_size,
                              hipStream_t stream) {
    const float* data    = (const float*)d_in[0];
    const float* W       = (const float*)d_in[1];
    const float* gamma   = (const float*)d_in[2];
    const float* beta    = (const float*)d_in[3];
    const int*   in_idx  = (const int*)d_in[4];
    const int*   out_idx = (const int*)d_in[5];
    float* out = (float*)d_out;

    // workspace layout (all sections multiples of 4 u32 -> 16B alignment)
    u32* cnt     = (u32*)d_ws;                 // NBINS
    u32* off     = cnt + NBINS;                // NBINS+1 (pad to NBINS+4)
    u32* rec     = off + NBINS + 4;            // TOTAL_E + 16 (over-read pad)
    u32* partial = rec + TOTAL_E + 16;         // 128
    short* Wt    = (short*)(partial + 128);    // KK*COUT*CIN shorts = 27648 u32
    float* stats = (float*)(Wt + KK * COUT * CIN); // 128
    const size_t ws_needed =
        (size_t)(NBINS + NBINS + 4 + TOTAL_E + 16 + 128 + KK * COUT * CIN / 2 + 128) * 4;

    if (ws_size >= ws_needed) {
        hipMemsetAsync(cnt, 0, (size_t)NBINS * sizeof(u32), stream);
        hipMemsetAsync(stats, 0, 128 * sizeof(float), stream);

        w_convert<<<(KK * COUT * CIN + 255) / 256, 256, 0, stream>>>(W, Wt);
        bin_count<<<2048, 256, 0, stream>>>((const int4*)out_idx, cnt);
        scan_part<<<NBINS / 1024, 1024, 0, stream>>>(cnt, partial);
        scan_small<<<1, 1, 0, stream>>>(partial);
        scan_final<<<NBINS / 1024, 1024, 0, stream>>>(cnt, off, partial);
        bin_scatter<<<2048, 256, 0, stream>>>((const int4*)in_idx, (const int4*)out_idx, cnt, rec);
        range_accum<<<NR, 256, 0, stream>>>(data, Wt, off, rec, out, stats);
        bn_norm<<<2048, 256, 0, stream>>>(out, stats, gamma, beta);
    } else {
        float* stats_fb = (float*)d_ws;
        hipMemsetAsync(d_out, 0, (size_t)N_OUT * COUT * sizeof(float), stream);
        hipMemsetAsync(stats_fb, 0, 128 * sizeof(float), stream);
        conv_scatter_fb<<<KK * 256, 256, 0, stream>>>(data, W, in_idx, out_idx, out);
        bn_stats_fb<<<1024, 256, 0, stream>>>(out, stats_fb);
        bn_norm<<<2048, 256, 0, stream>>>(out, stats_fb, gamma, beta);
    }
}